// Round 11
// baseline (311.890 us; speedup 1.0000x reference)
//
#include <hip/hip_runtime.h>

#define Bb 16
#define Tt 12
#define Nn 1024
#define FIN 32
#define FOUT 64
#define KC 3
#define TF (Tt * FIN)    // 384  — (t,f) fused dim
#define NO (Tt * FOUT)   // 768

#define BM 128
#define BN 192
#define BK 64
#define NKT (Nn / BK)    // 16 K-tiles (K = j = 1024)

typedef __attribute__((ext_vector_type(8))) short short8;
typedef __attribute__((ext_vector_type(4))) float f32x4;

__device__ __forceinline__ unsigned short f2bf(float f) {
  union { float f; unsigned u; } v; v.f = f;
  unsigned r = v.u + 0x7FFFu + ((v.u >> 16) & 1u);  // RNE
  return (unsigned short)(r >> 16);
}

__device__ __forceinline__ void BAR() {
  __builtin_amdgcn_sched_barrier(0);
  __builtin_amdgcn_s_barrier();
  __builtin_amdgcn_sched_barrier(0);
}

// ---------------------------------------------------------------------------
// k2r: YxT[b][t*32+f][j] = bf16(x[b,t,j,f]) — LDS-tiled transpose. (UNCHANGED)
// ---------------------------------------------------------------------------
__global__ __launch_bounds__(256) void k2r_build_YxT(
    const float* __restrict__ x, unsigned short* __restrict__ YxT) {
  __shared__ float xs[256][33];   // +1 pad
  const int tid = threadIdx.x;
  const int bid = blockIdx.x;     // (b*12 + t)*4 + jc
  const int jc = bid & 3;
  const int bt = bid >> 2;
  const int t = bt % Tt, b = bt / Tt;
  const int j0 = jc * 256;
  const float* xp = x + ((size_t)(b * Tt + t) * Nn + j0) * FIN;
#pragma unroll
  for (int m = 0; m < 8; ++m) {
    const int flat = m * 256 + tid;        // 0..2047 float4s
    const int j_loc = flat >> 3, f4 = flat & 7;
    const float4 v = *(const float4*)(xp + (size_t)j_loc * FIN + f4 * 4);
    xs[j_loc][f4 * 4 + 0] = v.x; xs[j_loc][f4 * 4 + 1] = v.y;
    xs[j_loc][f4 * 4 + 2] = v.z; xs[j_loc][f4 * 4 + 3] = v.w;
  }
  __syncthreads();
  const int f = tid >> 3, jg = tid & 7;    // 32 f-rows × 8 j-groups
  unsigned short* dst = YxT + ((size_t)b * TF + t * FIN + f) * Nn + j0 + jg * 32;
#pragma unroll
  for (int m = 0; m < 4; ++m) {
    short8 sh;
#pragma unroll
    for (int e = 0; e < 8; ++e)
      sh[e] = (short)f2bf(xs[jg * 32 + m * 8 + e][f]);
    *(short8*)(dst + m * 8) = sh;
  }
}

// ---------------------------------------------------------------------------
// k3f: FUSED A-build + GEMM, R11: deep reg-prefetch pipeline.
//   rhs[b][k][i][tf] = sum_j (cheb[k,i,j]*att[b,i,j])_bf16 * YxT[b][tf][j]
// Reg sets 0/1 double-buffer the att/cheb f32 prefetch (ISSUE(tau+3) at
// HEAD of iter tau -> ~2 iterations of latency cover); per-tile sync is
// vmcnt(8) (keeps this iter's 8 reg-loads in flight; drains ISSUE(tau+2)
// [CVTW operand] + BDMA(tau+1) [published by BAR]) — never 0 until tail.
// Queue walk verified for all iters; hazard proof as R9/R10.
// ---------------------------------------------------------------------------
#define ISSUE_SET(RA, RC, kt) do {                                          \
  _Pragma("unroll")                                                         \
  for (int u_ = 0; u_ < 2; ++u_) {                                          \
    const int idx_ = u_ * 512 + tid;                                        \
    const int row_ = idx_ >> 3, c_ = idx_ & 7;                              \
    const float* ap_ = Aa + (size_t)row_ * Nn + (kt) * BK + c_ * 8;         \
    const float* cp_ = Ac + (size_t)row_ * Nn + (kt) * BK + c_ * 8;         \
    RA[2 * u_]     = *(const float4*)ap_;                                   \
    RA[2 * u_ + 1] = *(const float4*)(ap_ + 4);                             \
    RC[2 * u_]     = *(const float4*)cp_;                                   \
    RC[2 * u_ + 1] = *(const float4*)(cp_ + 4);                             \
  }                                                                         \
} while (0)

#define CVTW_SET(RA, RC, D) do {                                            \
  _Pragma("unroll")                                                         \
  for (int u_ = 0; u_ < 2; ++u_) {                                          \
    const int idx_ = u_ * 512 + tid;                                        \
    const int row_ = idx_ >> 3, c_ = idx_ & 7;                              \
    short8 o_;                                                              \
    o_[0] = (short)f2bf(RA[2 * u_].x * RC[2 * u_].x);                       \
    o_[1] = (short)f2bf(RA[2 * u_].y * RC[2 * u_].y);                       \
    o_[2] = (short)f2bf(RA[2 * u_].z * RC[2 * u_].z);                       \
    o_[3] = (short)f2bf(RA[2 * u_].w * RC[2 * u_].w);                       \
    o_[4] = (short)f2bf(RA[2 * u_ + 1].x * RC[2 * u_ + 1].x);               \
    o_[5] = (short)f2bf(RA[2 * u_ + 1].y * RC[2 * u_ + 1].y);               \
    o_[6] = (short)f2bf(RA[2 * u_ + 1].z * RC[2 * u_ + 1].z);               \
    o_[7] = (short)f2bf(RA[2 * u_ + 1].w * RC[2 * u_ + 1].w);               \
    *(short8*)&lds[(D) * 8192 + row_ * 64 + (c_ ^ (row_ & 7)) * 8] = o_;    \
  }                                                                         \
} while (0)

__global__ __launch_bounds__(512, 4) void k3f_gemm(
    const float* __restrict__ att, const float* __restrict__ cheb,
    const unsigned short* __restrict__ YxT, unsigned short* __restrict__ rhs) {
  __shared__ __align__(16) unsigned short lds[40960];  // A 2×16KB, B 2×24KB
  const int bid = blockIdx.x;
  // 768 blocks; 6 siblings (3kk × 2nt) sharing one (b,it) att panel adjacent
  // on one XCD (R10 grouping, FETCH-verified).
  const int logical = (bid & 7) * 96 + (bid >> 3);   // bijective
  const int g = logical / 6, m = logical % 6;
  const int b  = g >> 3;
  const int it = g & 7;
  const int kk = m >> 1;
  const int nt = m & 1;
  const int bk = b * 3 + kk;
  const float* Aa = att  + ((size_t)b  * Nn + it * BM) * Nn;   // f32 panel
  const float* Ac = cheb + ((size_t)kk * Nn + it * BM) * Nn;   // f32 panel
  const unsigned short* Bp = YxT + ((size_t)b * TF + nt * BN) * Nn;
  const int tid = threadIdx.x;
  const int w = tid >> 6, l = tid & 63;
  const int wm = w >> 2, wn = w & 3;     // 2M × 4N (wave 64×48)
  const int lrow = l & 15;
  const int c0 = l >> 4;
  const int sx = lrow & 7;

  f32x4 acc[4][3];
#pragma unroll
  for (int mi = 0; mi < 4; ++mi)
#pragma unroll
    for (int ni = 0; ni < 3; ++ni)
      acc[mi][ni] = (f32x4){0.f, 0.f, 0.f, 0.f};

  float4 ra0[4], rc0[4], ra1[4], rc1[4];   // double-buffered prefetch sets

  auto BDMA = [&](int d, int kt) {       // B via global_load_lds
#pragma unroll
    for (int g2 = 0; g2 < 3; ++g2) {
      const int idx = g2 * 512 + tid;    // 0..1535
      const int row = idx >> 3;
      const int csrc = (idx & 7) ^ (row & 7);
      __builtin_amdgcn_global_load_lds(
          (const __attribute__((address_space(1))) void*)(Bp + (size_t)row * Nn + kt * BK + csrc * 8),
          (__attribute__((address_space(3))) void*)(lds + 16384 + d * 12288 + (g2 * 512 + w * 64) * 8),
          16, 0, 0);
    }
  };

  auto LDA = [&](int d, int mi, int ks) -> short8 {
    const int row = wm * 64 + mi * 16 + lrow;       // 0..127
    const int ch  = (c0 | (ks << 2)) ^ sx;
    return *(const short8*)&lds[d * 8192 + row * 64 + ch * 8];
  };
  auto LDB = [&](int d, int ni, int ks) -> short8 {
    const int row = wn * 48 + ni * 16 + lrow;       // 0..191
    const int ch  = (c0 | (ks << 2)) ^ sx;
    return *(const short8*)&lds[16384 + d * 12288 + row * 64 + ch * 8];
  };

  auto COMPUTE = [&](int d) {
    short8 bf[3];
    __builtin_amdgcn_s_setprio(1);
#pragma unroll
    for (int ni = 0; ni < 3; ++ni) bf[ni] = LDB(d, ni, 0);
#pragma unroll
    for (int mi = 0; mi < 4; ++mi) {
      const short8 af = LDA(d, mi, 0);
#pragma unroll
      for (int ni = 0; ni < 3; ++ni)
        acc[mi][ni] = __builtin_amdgcn_mfma_f32_16x16x32_bf16(af, bf[ni], acc[mi][ni], 0, 0, 0);
    }
#pragma unroll
    for (int ni = 0; ni < 3; ++ni) bf[ni] = LDB(d, ni, 1);
#pragma unroll
    for (int mi = 0; mi < 4; ++mi) {
      const short8 af = LDA(d, mi, 1);
#pragma unroll
      for (int ni = 0; ni < 3; ++ni)
        acc[mi][ni] = __builtin_amdgcn_mfma_f32_16x16x32_bf16(af, bf[ni], acc[mi][ni], 0, 0, 0);
    }
    __builtin_amdgcn_s_setprio(0);
  };

  // ---- prologue: tiles 0,1 built; ISSUE(2) in flight (kept by vmcnt(8)) ----
  ISSUE_SET(ra0, rc0, 0);
  asm volatile("s_waitcnt vmcnt(0)" ::: "memory");
  CVTW_SET(ra0, rc0, 0);
  ISSUE_SET(ra1, rc1, 1);
  asm volatile("s_waitcnt vmcnt(0)" ::: "memory");
  CVTW_SET(ra1, rc1, 1);
  BDMA(0, 0);
  BDMA(1, 1);
  ISSUE_SET(ra0, rc0, 2);
  asm volatile("s_waitcnt vmcnt(8) lgkmcnt(0)" ::: "memory");  // drain BDMAs+writes, keep ISSUE(2)
  BAR();

  for (int tp = 0; tp < NKT / 2; ++tp) {
    const int t0 = 2 * tp;
    // ---- iter t0 (buf 0): head-prefetch set1 <- tile t0+3 ----
    if (t0 + 3 < NKT) { ISSUE_SET(ra1, rc1, t0 + 3); }
    COMPUTE(0);
    if (t0 + 3 < NKT) asm volatile("s_waitcnt vmcnt(8) lgkmcnt(0)" ::: "memory");
    else              asm volatile("s_waitcnt vmcnt(0) lgkmcnt(0)" ::: "memory");
    BAR();
    if (t0 + 2 < NKT) { CVTW_SET(ra0, rc0, 0); BDMA(0, t0 + 2); }
    __builtin_amdgcn_sched_barrier(0);
    // ---- iter t1 = t0+1 (buf 1): head-prefetch set0 <- tile t1+3 ----
    const int t1 = t0 + 1;
    if (t1 + 3 < NKT) { ISSUE_SET(ra0, rc0, t1 + 3); }
    COMPUTE(1);
    if (t1 + 3 < NKT) asm volatile("s_waitcnt vmcnt(8) lgkmcnt(0)" ::: "memory");
    else              asm volatile("s_waitcnt vmcnt(0) lgkmcnt(0)" ::: "memory");
    BAR();
    if (t1 + 2 < NKT) { CVTW_SET(ra1, rc1, 1); BDMA(1, t1 + 2); }
    __builtin_amdgcn_sched_barrier(0);
  }
  asm volatile("s_waitcnt vmcnt(0)" ::: "memory");

  // C-write: rhs[(bk*1024 + it*128 + row)][nt*192 + col] bf16
  unsigned short* Cw = rhs + ((size_t)bk * Nn + it * BM) * TF + nt * BN;
#pragma unroll
  for (int mi = 0; mi < 4; ++mi) {
#pragma unroll
    for (int ni = 0; ni < 3; ++ni) {
      const int col = wn * 48 + ni * 16 + lrow;
      const int row0 = wm * 64 + mi * 16 + c0 * 4;
      unsigned short* op = Cw + (size_t)row0 * TF + col;
      f32x4 v = acc[mi][ni];
#pragma unroll
      for (int q = 0; q < 4; ++q)
        op[(size_t)q * TF] = f2bf(v[q]);
    }
  }
}

// ---------------------------------------------------------------------------
// k4: out[b,t,i,o] = relu( sum_{k,f} rhs[b,k,i,t*32+f] * Theta[k,f,o] )
// (UNCHANGED)
// ---------------------------------------------------------------------------
__global__ __launch_bounds__(256) void k4_epilogue(
    const unsigned short* __restrict__ rhs, const float* __restrict__ theta,
    float* __restrict__ out) {
  __shared__ float th[KC * FIN * FOUT];  // 24 KB, [kf][o]
  const int tid = threadIdx.x;
  for (int s = tid; s < KC * FIN * FOUT; s += 256) th[s] = theta[s];
  __syncthreads();
  const int bid = blockIdx.x;            // (b*12 + t)*4 + ic
  const int ic = bid & 3;
  const int bt = bid >> 2;
  const int t = bt % Tt, b = bt / Tt;
  const int w = tid >> 6, l = tid & 63;
  const int lrow = l & 15;
  const int c0 = l >> 4;
  const int i0 = ic * 256 + w * 64;

  short8 bfrag[KC][4];
#pragma unroll
  for (int ks = 0; ks < KC; ++ks)
#pragma unroll
    for (int oi = 0; oi < 4; ++oi) {
      short8 bf;
#pragma unroll
      for (int rr = 0; rr < 8; ++rr)
        bf[rr] = (short)f2bf(th[(ks * FIN + c0 * 8 + rr) * FOUT + oi * 16 + lrow]);
      bfrag[ks][oi] = bf;
    }

  f32x4 acc[4][4];
#pragma unroll
  for (int mi = 0; mi < 4; ++mi)
#pragma unroll
    for (int oi = 0; oi < 4; ++oi)
      acc[mi][oi] = (f32x4){0.f, 0.f, 0.f, 0.f};

#pragma unroll
  for (int ks = 0; ks < KC; ++ks) {
#pragma unroll
    for (int mi = 0; mi < 4; ++mi) {
      const short8 af = *(const short8*)(
          rhs + ((size_t)(b * KC + ks) * Nn + i0 + mi * 16 + lrow) * TF + t * FIN + c0 * 8);
#pragma unroll
      for (int oi = 0; oi < 4; ++oi)
        acc[mi][oi] = __builtin_amdgcn_mfma_f32_16x16x32_bf16(af, bfrag[ks][oi], acc[mi][oi], 0, 0, 0);
    }
  }

#pragma unroll
  for (int mi = 0; mi < 4; ++mi) {
#pragma unroll
    for (int oi = 0; oi < 4; ++oi) {
      const int row = i0 + mi * 16 + c0 * 4;
      float* op = out + ((size_t)(b * Tt + t) * Nn + row) * FOUT + oi * 16 + lrow;
      f32x4 v = acc[mi][oi];
#pragma unroll
      for (int q = 0; q < 4; ++q)
        op[(size_t)q * FOUT] = fmaxf(v[q], 0.f);
    }
  }
}

// ---------------------------------------------------------------------------
// fallback (ws too small): slow but correct, pure f32
// ---------------------------------------------------------------------------
__global__ __launch_bounds__(128) void k_fallback(
    const float* __restrict__ x, const float* __restrict__ att,
    const float* __restrict__ cheb, const float* __restrict__ theta,
    float* __restrict__ out) {
  const int blk = blockIdx.x;  // (b, t, i)
  const int i = blk & 1023;
  const int bt = blk >> 10;
  const int t = bt % Tt, b = bt / Tt;
  __shared__ float rhs[KC * FIN];
  const int tid = threadIdx.x;
  if (tid < KC * FIN) {
    const int k = tid >> 5, f = tid & 31;
    const float* ar = att + ((size_t)b * Nn + i) * Nn;
    const float* cr = cheb + ((size_t)k * Nn + i) * Nn;
    const float* xr = x + ((size_t)(b * Tt + t) * Nn) * FIN + f;
    float s = 0.f;
    for (int j = 0; j < Nn; ++j) s = fmaf(ar[j] * cr[j], xr[(size_t)j * FIN], s);
    rhs[tid] = s;
  }
  __syncthreads();
  if (tid < FOUT) {
    float a = 0.f;
#pragma unroll
    for (int kf = 0; kf < KC * FIN; ++kf) a = fmaf(rhs[kf], theta[kf * FOUT + tid], a);
    out[((size_t)(b * Tt + t) * Nn + i) * FOUT + tid] = fmaxf(a, 0.f);
  }
}

extern "C" void kernel_launch(void* const* d_in, const int* in_sizes, int n_in,
                              void* d_out, int out_size, void* d_ws, size_t ws_size,
                              hipStream_t stream) {
  const float* x     = (const float*)d_in[0];
  const float* att   = (const float*)d_in[1];
  const float* cheb  = (const float*)d_in[2];
  const float* theta = (const float*)d_in[3];
  float* out = (float*)d_out;

  const size_t needYx = (size_t)Bb * TF * Nn * sizeof(unsigned short);      // 12.6 MB
  const size_t needR  = (size_t)Bb * KC * Nn * TF * sizeof(unsigned short); // 37.7 MB
  if (ws_size >= needYx + needR) {
    unsigned short* YxT = (unsigned short*)d_ws;
    unsigned short* rhs = (unsigned short*)((char*)d_ws + needYx);
    hipLaunchKernelGGL(k2r_build_YxT, dim3(Bb * Tt * 4), dim3(256), 0, stream,
                       x, YxT);
    hipLaunchKernelGGL(k3f_gemm, dim3(48 * (Nn / BM) * (TF / BN)), dim3(512), 0, stream,
                       att, cheb, YxT, rhs);
    hipLaunchKernelGGL(k4_epilogue, dim3(Bb * Tt * 4), dim3(256), 0, stream,
                       rhs, theta, out);
  } else {
    hipLaunchKernelGGL(k_fallback, dim3(Bb * Tt * Nn), dim3(128), 0, stream,
                       x, att, cheb, theta, out);
  }
}

// Round 13
// 121.744 us; speedup vs baseline: 2.5619x; 2.5619x over previous
//
#include <hip/hip_runtime.h>

#define Bb 16
#define Tt 12
#define Nn 1024
#define FIN 32
#define FOUT 64
#define KC 3
#define TF (Tt * FIN)    // 384  — (t,f) fused dim
#define NO (Tt * FOUT)   // 768

#define BM 128
#define BN 192
#define BK 64
#define NKT 16           // k-tiles per kk pass
#define NIT (KC * NKT)   // 48 continuous iterations

typedef __attribute__((ext_vector_type(8))) short short8;
typedef __attribute__((ext_vector_type(4))) float f32x4;

__device__ __forceinline__ unsigned short f2bf(float f) {
  union { float f; unsigned u; } v; v.f = f;
  unsigned r = v.u + 0x7FFFu + ((v.u >> 16) & 1u);  // RNE
  return (unsigned short)(r >> 16);
}

__device__ __forceinline__ void BAR() {
  __builtin_amdgcn_sched_barrier(0);
  __builtin_amdgcn_s_barrier();
  __builtin_amdgcn_sched_barrier(0);
}

// ---------------------------------------------------------------------------
// k2r: YxT[b][t*32+f][j] = bf16(x[b,t,j,f]) — LDS-tiled transpose. (UNCHANGED)
// ---------------------------------------------------------------------------
__global__ __launch_bounds__(256) void k2r_build_YxT(
    const float* __restrict__ x, unsigned short* __restrict__ YxT) {
  __shared__ float xs[256][33];   // +1 pad
  const int tid = threadIdx.x;
  const int bid = blockIdx.x;     // (b*12 + t)*4 + jc
  const int jc = bid & 3;
  const int bt = bid >> 2;
  const int t = bt % Tt, b = bt / Tt;
  const int j0 = jc * 256;
  const float* xp = x + ((size_t)(b * Tt + t) * Nn + j0) * FIN;
#pragma unroll
  for (int m = 0; m < 8; ++m) {
    const int flat = m * 256 + tid;        // 0..2047 float4s
    const int j_loc = flat >> 3, f4 = flat & 7;
    const float4 v = *(const float4*)(xp + (size_t)j_loc * FIN + f4 * 4);
    xs[j_loc][f4 * 4 + 0] = v.x; xs[j_loc][f4 * 4 + 1] = v.y;
    xs[j_loc][f4 * 4 + 2] = v.z; xs[j_loc][f4 * 4 + 3] = v.w;
  }
  __syncthreads();
  const int f = tid >> 3, jg = tid & 7;    // 32 f-rows × 8 j-groups
  unsigned short* dst = YxT + ((size_t)b * TF + t * FIN + f) * Nn + j0 + jg * 32;
#pragma unroll
  for (int m = 0; m < 4; ++m) {
    short8 sh;
#pragma unroll
    for (int e = 0; e < 8; ++e)
      sh[e] = (short)f2bf(xs[jg * 32 + m * 8 + e][f]);
    *(short8*)(dst + m * 8) = sh;
  }
}

// ---------------------------------------------------------------------------
// k3f2: FUSED A-build + GEMM, kk-outer continuation (R12 structure; R13
// fixes the launch grid: 256 blocks — the /KC was a leftover R10 divisor
// that silently launched 85 blocks).
// Block = (b, it, nt): 256 blocks = 1/CU, zero packing tail. 48 continuous
// iterations (kk = ii/16 embedded; acc reused per pass, C-write at pass end).
// B ring 4-deep (tile +4 ahead) -> steady-state wait vmcnt(3): B-DMA NEVER
// drains (T4). A-source f32 regs ISSUE'd 1 iter ahead (L2-hot within block).
// LDS 128 KB: A 2x16KB + B 4x24KB.
// Ledger (verified): outstanding at Wait(k) = {BDMA(k+2)x3, ISSUE(k+2)x8,
// BDMA(k+3)x3}; vmcnt(3) keeps exactly BDMA(k+3). Register consumers are
// additionally guarded by compiler auto-waits; LDS-DMA visibility by the
// manual vmcnt + BAR; WAR by lgkm(0)+BAR before restaging.
// ---------------------------------------------------------------------------
__global__ __launch_bounds__(512, 2) void k3f2_gemm(
    const float* __restrict__ att, const float* __restrict__ cheb,
    const unsigned short* __restrict__ YxT, unsigned short* __restrict__ rhs) {
  __shared__ __align__(16) unsigned short lds[65536];  // A 2*8192 + B 4*12288 ushorts
  const int bid = blockIdx.x;
  const int logical = (bid & 7) * 32 + (bid >> 3);  // 256 blocks, bijective XCD chunking
  const int g  = logical >> 1;       // (b,it): nt-pair adjacent on same XCD
  const int b  = g >> 3;
  const int it = g & 7;
  const int nt = logical & 1;
  const float* Aa = att + ((size_t)b * Nn + it * BM) * Nn;   // f32 att panel
  const unsigned short* Bp = YxT + ((size_t)b * TF + nt * BN) * Nn;
  const int tid = threadIdx.x;
  const int w = tid >> 6, l = tid & 63;
  const int wm = w >> 2, wn = w & 3;     // 2M × 4N (wave 64×48)
  const int lrow = l & 15;
  const int c0 = l >> 4;
  const int sx = lrow & 7;

  f32x4 acc[4][3];
#pragma unroll
  for (int mi = 0; mi < 4; ++mi)
#pragma unroll
    for (int ni = 0; ni < 3; ++ni)
      acc[mi][ni] = (f32x4){0.f, 0.f, 0.f, 0.f};

  float4 ra[4], rc[4];   // single prefetch set (32 VGPR), 1-iter lifetime

  // ISSUE: load att + cheb[kk(tile)] f32 for tile index tt (0..47)
  auto ISSUE = [&](int tt) {
    const int kkp = tt >> 4, ktp = tt & 15;
    const float* Ac = cheb + ((size_t)kkp * Nn + it * BM) * Nn;
#pragma unroll
    for (int u = 0; u < 2; ++u) {
      const int idx = u * 512 + tid;     // 0..1023 = row*8 + c
      const int row = idx >> 3, c = idx & 7;
      const float* ap = Aa + (size_t)row * Nn + ktp * BK + c * 8;
      const float* cp = Ac + (size_t)row * Nn + ktp * BK + c * 8;
      ra[2 * u]     = *(const float4*)ap;
      ra[2 * u + 1] = *(const float4*)(ap + 4);
      rc[2 * u]     = *(const float4*)cp;
      rc[2 * u + 1] = *(const float4*)(cp + 4);
    }
  };

  auto CVTW = [&](int d) {               // products -> bf16 -> swizzled ds_write
#pragma unroll
    for (int u = 0; u < 2; ++u) {
      const int idx = u * 512 + tid;
      const int row = idx >> 3, c = idx & 7;
      short8 o;
      o[0] = (short)f2bf(ra[2 * u].x * rc[2 * u].x);
      o[1] = (short)f2bf(ra[2 * u].y * rc[2 * u].y);
      o[2] = (short)f2bf(ra[2 * u].z * rc[2 * u].z);
      o[3] = (short)f2bf(ra[2 * u].w * rc[2 * u].w);
      o[4] = (short)f2bf(ra[2 * u + 1].x * rc[2 * u + 1].x);
      o[5] = (short)f2bf(ra[2 * u + 1].y * rc[2 * u + 1].y);
      o[6] = (short)f2bf(ra[2 * u + 1].z * rc[2 * u + 1].z);
      o[7] = (short)f2bf(ra[2 * u + 1].w * rc[2 * u + 1].w);
      *(short8*)&lds[d * 8192 + row * 64 + (c ^ (row & 7)) * 8] = o;
    }
  };

  auto BDMA = [&](int q, int tt) {       // B tile (kt only) -> ring buf q
    const int ktp = tt & 15;
#pragma unroll
    for (int g2 = 0; g2 < 3; ++g2) {
      const int idx = g2 * 512 + tid;    // 0..1535
      const int row = idx >> 3;
      const int csrc = (idx & 7) ^ (row & 7);
      __builtin_amdgcn_global_load_lds(
          (const __attribute__((address_space(1))) void*)(Bp + (size_t)row * Nn + ktp * BK + csrc * 8),
          (__attribute__((address_space(3))) void*)(lds + 16384 + q * 12288 + (g2 * 512 + w * 64) * 8),
          16, 0, 0);
    }
  };

  auto LDA = [&](int d, int mi, int ks) -> short8 {
    const int row = wm * 64 + mi * 16 + lrow;       // 0..127
    const int ch  = (c0 | (ks << 2)) ^ sx;
    return *(const short8*)&lds[d * 8192 + row * 64 + ch * 8];
  };
  auto LDB = [&](int q, int ni, int ks) -> short8 {
    const int row = wn * 48 + ni * 16 + lrow;       // 0..191
    const int ch  = (c0 | (ks << 2)) ^ sx;
    return *(const short8*)&lds[16384 + q * 12288 + row * 64 + ch * 8];
  };

  // ---- prologue: A tiles 0,1 built; B tiles 0-3 in ring; ISSUE(2) flying ----
  ISSUE(0);
  asm volatile("s_waitcnt vmcnt(0)" ::: "memory");
  CVTW(0);
  ISSUE(1);
  asm volatile("s_waitcnt vmcnt(0)" ::: "memory");
  CVTW(1);
  BDMA(0, 0); BDMA(1, 1); BDMA(2, 2); BDMA(3, 3);
  ISSUE(2);
  asm volatile("s_waitcnt vmcnt(8) lgkmcnt(0)" ::: "memory");  // drain BDMAs+writes, keep ISSUE(2)
  BAR();

  for (int ii = 0; ii < NIT; ++ii) {
    const int d = ii & 1, q = ii & 3;
    short8 bf[3];
    __builtin_amdgcn_s_setprio(1);
#pragma unroll
    for (int ni = 0; ni < 3; ++ni) bf[ni] = LDB(q, ni, 0);
#pragma unroll
    for (int mi = 0; mi < 4; ++mi) {
      const short8 af = LDA(d, mi, 0);
#pragma unroll
      for (int ni = 0; ni < 3; ++ni)
        acc[mi][ni] = __builtin_amdgcn_mfma_f32_16x16x32_bf16(af, bf[ni], acc[mi][ni], 0, 0, 0);
    }
#pragma unroll
    for (int ni = 0; ni < 3; ++ni) bf[ni] = LDB(q, ni, 1);
#pragma unroll
    for (int mi = 0; mi < 4; ++mi) {
      const short8 af = LDA(d, mi, 1);
#pragma unroll
      for (int ni = 0; ni < 3; ++ni)
        acc[mi][ni] = __builtin_amdgcn_mfma_f32_16x16x32_bf16(af, bf[ni], acc[mi][ni], 0, 0, 0);
    }
    __builtin_amdgcn_s_setprio(0);
    // steady: keep the 3 newest (last tail's BDMA) in flight; drain ISSUE(ii+2)
    // (CVTW below) + everything older. Tail iters drain fully.
    if (ii <= NIT - 4) asm volatile("s_waitcnt vmcnt(3) lgkmcnt(0)" ::: "memory");
    else               asm volatile("s_waitcnt vmcnt(0) lgkmcnt(0)" ::: "memory");
    BAR();
    if ((ii & 15) == 15) {
      // pass boundary: write rhs for kk = ii>>4, reset acc
      const int kk = ii >> 4;
      unsigned short* Cw = rhs + ((size_t)(b * KC + kk) * Nn + it * BM) * TF + nt * BN;
#pragma unroll
      for (int mi = 0; mi < 4; ++mi) {
#pragma unroll
        for (int ni = 0; ni < 3; ++ni) {
          const int col = wn * 48 + ni * 16 + lrow;
          const int row0 = wm * 64 + mi * 16 + c0 * 4;
          unsigned short* op = Cw + (size_t)row0 * TF + col;
          f32x4 v = acc[mi][ni];
#pragma unroll
          for (int qq = 0; qq < 4; ++qq)
            op[(size_t)qq * TF] = f2bf(v[qq]);
          acc[mi][ni] = (f32x4){0.f, 0.f, 0.f, 0.f};
        }
      }
    }
    if (ii + 2 < NIT) CVTW(d);          // stage A tile ii+2 -> buf d (freed by BAR)
    if (ii + 3 < NIT) ISSUE(ii + 3);    // refill regs (consumed next iter's CVTW)
    if (ii + 4 < NIT) BDMA(q, ii + 4);  // B ring: issue LAST -> stays newest-3
    __builtin_amdgcn_sched_barrier(0);
  }
}

// ---------------------------------------------------------------------------
// k4: out[b,t,i,o] = relu( sum_{k,f} rhs[b,k,i,t*32+f] * Theta[k,f,o] )
// (UNCHANGED)
// ---------------------------------------------------------------------------
__global__ __launch_bounds__(256) void k4_epilogue(
    const unsigned short* __restrict__ rhs, const float* __restrict__ theta,
    float* __restrict__ out) {
  __shared__ float th[KC * FIN * FOUT];  // 24 KB, [kf][o]
  const int tid = threadIdx.x;
  for (int s = tid; s < KC * FIN * FOUT; s += 256) th[s] = theta[s];
  __syncthreads();
  const int bid = blockIdx.x;            // (b*12 + t)*4 + ic
  const int ic = bid & 3;
  const int bt = bid >> 2;
  const int t = bt % Tt, b = bt / Tt;
  const int w = tid >> 6, l = tid & 63;
  const int lrow = l & 15;
  const int c0 = l >> 4;
  const int i0 = ic * 256 + w * 64;

  short8 bfrag[KC][4];
#pragma unroll
  for (int ks = 0; ks < KC; ++ks)
#pragma unroll
    for (int oi = 0; oi < 4; ++oi) {
      short8 bf;
#pragma unroll
      for (int rr = 0; rr < 8; ++rr)
        bf[rr] = (short)f2bf(th[(ks * FIN + c0 * 8 + rr) * FOUT + oi * 16 + lrow]);
      bfrag[ks][oi] = bf;
    }

  f32x4 acc[4][4];
#pragma unroll
  for (int mi = 0; mi < 4; ++mi)
#pragma unroll
    for (int oi = 0; oi < 4; ++oi)
      acc[mi][oi] = (f32x4){0.f, 0.f, 0.f, 0.f};

#pragma unroll
  for (int ks = 0; ks < KC; ++ks) {
#pragma unroll
    for (int mi = 0; mi < 4; ++mi) {
      const short8 af = *(const short8*)(
          rhs + ((size_t)(b * KC + ks) * Nn + i0 + mi * 16 + lrow) * TF + t * FIN + c0 * 8);
#pragma unroll
      for (int oi = 0; oi < 4; ++oi)
        acc[mi][oi] = __builtin_amdgcn_mfma_f32_16x16x32_bf16(af, bfrag[ks][oi], acc[mi][oi], 0, 0, 0);
    }
  }

#pragma unroll
  for (int mi = 0; mi < 4; ++mi) {
#pragma unroll
    for (int oi = 0; oi < 4; ++oi) {
      const int row = i0 + mi * 16 + c0 * 4;
      float* op = out + ((size_t)(b * Tt + t) * Nn + row) * FOUT + oi * 16 + lrow;
      f32x4 v = acc[mi][oi];
#pragma unroll
      for (int q = 0; q < 4; ++q)
        op[(size_t)q * FOUT] = fmaxf(v[q], 0.f);
    }
  }
}

// ---------------------------------------------------------------------------
// fallback (ws too small): slow but correct, pure f32
// ---------------------------------------------------------------------------
__global__ __launch_bounds__(128) void k_fallback(
    const float* __restrict__ x, const float* __restrict__ att,
    const float* __restrict__ cheb, const float* __restrict__ theta,
    float* __restrict__ out) {
  const int blk = blockIdx.x;  // (b, t, i)
  const int i = blk & 1023;
  const int bt = blk >> 10;
  const int t = bt % Tt, b = bt / Tt;
  __shared__ float rhs[KC * FIN];
  const int tid = threadIdx.x;
  if (tid < KC * FIN) {
    const int k = tid >> 5, f = tid & 31;
    const float* ar = att + ((size_t)b * Nn + i) * Nn;
    const float* cr = cheb + ((size_t)k * Nn + i) * Nn;
    const float* xr = x + ((size_t)(b * Tt + t) * Nn) * FIN + f;
    float s = 0.f;
    for (int j = 0; j < Nn; ++j) s = fmaf(ar[j] * cr[j], xr[(size_t)j * FIN], s);
    rhs[tid] = s;
  }
  __syncthreads();
  if (tid < FOUT) {
    float a = 0.f;
#pragma unroll
    for (int kf = 0; kf < KC * FIN; ++kf) a = fmaf(rhs[kf], theta[kf * FOUT + tid], a);
    out[((size_t)(b * Tt + t) * Nn + i) * FOUT + tid] = fmaxf(a, 0.f);
  }
}

extern "C" void kernel_launch(void* const* d_in, const int* in_sizes, int n_in,
                              void* d_out, int out_size, void* d_ws, size_t ws_size,
                              hipStream_t stream) {
  const float* x     = (const float*)d_in[0];
  const float* att   = (const float*)d_in[1];
  const float* cheb  = (const float*)d_in[2];
  const float* theta = (const float*)d_in[3];
  float* out = (float*)d_out;

  const size_t needYx = (size_t)Bb * TF * Nn * sizeof(unsigned short);      // 12.6 MB
  const size_t needR  = (size_t)Bb * KC * Nn * TF * sizeof(unsigned short); // 37.7 MB
  if (ws_size >= needYx + needR) {
    unsigned short* YxT = (unsigned short*)d_ws;
    unsigned short* rhs = (unsigned short*)((char*)d_ws + needYx);
    hipLaunchKernelGGL(k2r_build_YxT, dim3(Bb * Tt * 4), dim3(256), 0, stream,
                       x, YxT);
    // R13 fix: 256 blocks = (b, it, nt) — kk is folded INSIDE the kernel.
    hipLaunchKernelGGL(k3f2_gemm, dim3(Bb * (Nn / BM) * (TF / BN)), dim3(512), 0, stream,
                       att, cheb, YxT, rhs);
    hipLaunchKernelGGL(k4_epilogue, dim3(Bb * Tt * 4), dim3(256), 0, stream,
                       rhs, theta, out);
  } else {
    hipLaunchKernelGGL(k_fallback, dim3(Bb * Tt * Nn), dim3(128), 0, stream,
                       x, att, cheb, theta, out);
  }
}

// Round 14
// 100.468 us; speedup vs baseline: 3.1044x; 1.2118x over previous
//
#include <hip/hip_runtime.h>

#define Bb 16
#define Tt 12
#define Nn 1024
#define FIN 32
#define FOUT 64
#define KC 3
#define TF (Tt * FIN)    // 384  — (t,f) fused dim
#define NO (Tt * FOUT)   // 768

#define BM 128
#define BN 192
#define BK 64
#define NKT (Nn / BK)    // 16 K-tiles (K = j = 1024)

typedef __attribute__((ext_vector_type(8))) short short8;
typedef __attribute__((ext_vector_type(4))) float f32x4;

__device__ __forceinline__ unsigned short f2bf(float f) {
  union { float f; unsigned u; } v; v.f = f;
  unsigned r = v.u + 0x7FFFu + ((v.u >> 16) & 1u);  // RNE
  return (unsigned short)(r >> 16);
}

__device__ __forceinline__ void BAR() {
  __builtin_amdgcn_sched_barrier(0);
  __builtin_amdgcn_s_barrier();
  __builtin_amdgcn_sched_barrier(0);
}

// ---------------------------------------------------------------------------
// k2r: YxT[b][t*32+f][j] = bf16(x[b,t,j,f]) — LDS-tiled transpose. (UNCHANGED)
// ---------------------------------------------------------------------------
__global__ __launch_bounds__(256) void k2r_build_YxT(
    const float* __restrict__ x, unsigned short* __restrict__ YxT) {
  __shared__ float xs[256][33];   // +1 pad
  const int tid = threadIdx.x;
  const int bid = blockIdx.x;     // (b*12 + t)*4 + jc
  const int jc = bid & 3;
  const int bt = bid >> 2;
  const int t = bt % Tt, b = bt / Tt;
  const int j0 = jc * 256;
  const float* xp = x + ((size_t)(b * Tt + t) * Nn + j0) * FIN;
#pragma unroll
  for (int m = 0; m < 8; ++m) {
    const int flat = m * 256 + tid;        // 0..2047 float4s
    const int j_loc = flat >> 3, f4 = flat & 7;
    const float4 v = *(const float4*)(xp + (size_t)j_loc * FIN + f4 * 4);
    xs[j_loc][f4 * 4 + 0] = v.x; xs[j_loc][f4 * 4 + 1] = v.y;
    xs[j_loc][f4 * 4 + 2] = v.z; xs[j_loc][f4 * 4 + 3] = v.w;
  }
  __syncthreads();
  const int f = tid >> 3, jg = tid & 7;    // 32 f-rows × 8 j-groups
  unsigned short* dst = YxT + ((size_t)b * TF + t * FIN + f) * Nn + j0 + jg * 32;
#pragma unroll
  for (int m = 0; m < 4; ++m) {
    short8 sh;
#pragma unroll
    for (int e = 0; e < 8; ++e)
      sh[e] = (short)f2bf(xs[jg * 32 + m * 8 + e][f]);
    *(short8*)(dst + m * 8) = sh;
  }
}

// ---------------------------------------------------------------------------
// k3f: FUSED A-build + GEMM (R10 structure, R14 counted-wait retrofit).
//   rhs[b][k][i][tf] = sum_j (cheb[k,i,j]*att[b,i,j])_bf16 * YxT[b][tf][j]
// Per-tile sync is now vmcnt(8): drains only BDMA(tau+1) (3 oldest), keeps
// the 8 f32 ISSUE(tau+2) loads in flight across the barrier; their consumer
// (CVTW, post-barrier) gets a compiler counted wait that is ~free after a
// full COMPUTE of latency cover. Tail iters (tau > NKT-4) drain fully.
// Ledger at wait(tau): {BDMA(tau+1)x3 old, ISSUE(tau+2)x8 new} -> vmcnt(8).
// WAR: lgkm(0)+BAR before tail restaging (unchanged from R10, proven).
// ---------------------------------------------------------------------------
__global__ __launch_bounds__(512, 4) void k3f_gemm(
    const float* __restrict__ att, const float* __restrict__ cheb,
    const unsigned short* __restrict__ YxT, unsigned short* __restrict__ rhs) {
  __shared__ __align__(16) unsigned short lds[40960];  // A 2×16KB, B 2×24KB
  const int bid = blockIdx.x;
  // 768 blocks; 6 siblings (3kk × 2nt) sharing one (b,it) att panel adjacent
  // on one XCD (R10 grouping, FETCH-verified).
  const int logical = (bid & 7) * 96 + (bid >> 3);   // bijective
  const int g = logical / 6, m = logical % 6;
  const int b  = g >> 3;
  const int it = g & 7;
  const int kk = m >> 1;
  const int nt = m & 1;
  const int bk = b * 3 + kk;
  const float* Aa = att  + ((size_t)b  * Nn + it * BM) * Nn;   // f32 panel
  const float* Ac = cheb + ((size_t)kk * Nn + it * BM) * Nn;   // f32 panel
  const unsigned short* Bp = YxT + ((size_t)b * TF + nt * BN) * Nn;
  const int tid = threadIdx.x;
  const int w = tid >> 6, l = tid & 63;
  const int wm = w >> 2, wn = w & 3;     // 2M × 4N (wave 64×48)
  const int lrow = l & 15;
  const int c0 = l >> 4;
  const int sx = lrow & 7;

  f32x4 acc[4][3];
#pragma unroll
  for (int mi = 0; mi < 4; ++mi)
#pragma unroll
    for (int ni = 0; ni < 3; ++ni)
      acc[mi][ni] = (f32x4){0.f, 0.f, 0.f, 0.f};

  float4 ra[4], rc[4];   // single prefetch set (32 VGPR), 1-iter lifetime

  auto ISSUE = [&](int kt) {             // issue 8 dwordx4 loads -> ra/rc
#pragma unroll
    for (int u = 0; u < 2; ++u) {
      const int idx = u * 512 + tid;     // 0..1023 = row*8 + c
      const int row = idx >> 3, c = idx & 7;
      const float* ap = Aa + (size_t)row * Nn + kt * BK + c * 8;
      const float* cp = Ac + (size_t)row * Nn + kt * BK + c * 8;
      ra[2 * u]     = *(const float4*)ap;
      ra[2 * u + 1] = *(const float4*)(ap + 4);
      rc[2 * u]     = *(const float4*)cp;
      rc[2 * u + 1] = *(const float4*)(cp + 4);
    }
  };

  auto CVTW = [&](int d) {               // products -> bf16 -> swizzled ds_write
#pragma unroll
    for (int u = 0; u < 2; ++u) {
      const int idx = u * 512 + tid;
      const int row = idx >> 3, c = idx & 7;
      short8 o;
      o[0] = (short)f2bf(ra[2 * u].x * rc[2 * u].x);
      o[1] = (short)f2bf(ra[2 * u].y * rc[2 * u].y);
      o[2] = (short)f2bf(ra[2 * u].z * rc[2 * u].z);
      o[3] = (short)f2bf(ra[2 * u].w * rc[2 * u].w);
      o[4] = (short)f2bf(ra[2 * u + 1].x * rc[2 * u + 1].x);
      o[5] = (short)f2bf(ra[2 * u + 1].y * rc[2 * u + 1].y);
      o[6] = (short)f2bf(ra[2 * u + 1].z * rc[2 * u + 1].z);
      o[7] = (short)f2bf(ra[2 * u + 1].w * rc[2 * u + 1].w);
      *(short8*)&lds[d * 8192 + row * 64 + (c ^ (row & 7)) * 8] = o;
    }
  };

  auto BDMA = [&](int d, int kt) {       // B via global_load_lds
#pragma unroll
    for (int g2 = 0; g2 < 3; ++g2) {
      const int idx = g2 * 512 + tid;    // 0..1535
      const int row = idx >> 3;
      const int csrc = (idx & 7) ^ (row & 7);
      __builtin_amdgcn_global_load_lds(
          (const __attribute__((address_space(1))) void*)(Bp + (size_t)row * Nn + kt * BK + csrc * 8),
          (__attribute__((address_space(3))) void*)(lds + 16384 + d * 12288 + (g2 * 512 + w * 64) * 8),
          16, 0, 0);
    }
  };

  auto LDA = [&](int d, int mi, int ks) -> short8 {
    const int row = wm * 64 + mi * 16 + lrow;       // 0..127
    const int ch  = (c0 | (ks << 2)) ^ sx;
    return *(const short8*)&lds[d * 8192 + row * 64 + ch * 8];
  };
  auto LDB = [&](int d, int ni, int ks) -> short8 {
    const int row = wn * 48 + ni * 16 + lrow;       // 0..191
    const int ch  = (c0 | (ks << 2)) ^ sx;
    return *(const short8*)&lds[16384 + d * 12288 + row * 64 + ch * 8];
  };

  auto COMPUTE = [&](int d) {
    short8 bf[3];
    __builtin_amdgcn_s_setprio(1);
#pragma unroll
    for (int ni = 0; ni < 3; ++ni) bf[ni] = LDB(d, ni, 0);
#pragma unroll
    for (int mi = 0; mi < 4; ++mi) {
      const short8 af = LDA(d, mi, 0);
#pragma unroll
      for (int ni = 0; ni < 3; ++ni)
        acc[mi][ni] = __builtin_amdgcn_mfma_f32_16x16x32_bf16(af, bf[ni], acc[mi][ni], 0, 0, 0);
    }
#pragma unroll
    for (int ni = 0; ni < 3; ++ni) bf[ni] = LDB(d, ni, 1);
#pragma unroll
    for (int mi = 0; mi < 4; ++mi) {
      const short8 af = LDA(d, mi, 1);
#pragma unroll
      for (int ni = 0; ni < 3; ++ni)
        acc[mi][ni] = __builtin_amdgcn_mfma_f32_16x16x32_bf16(af, bf[ni], acc[mi][ni], 0, 0, 0);
    }
    __builtin_amdgcn_s_setprio(0);
  };

  // ---- prologue: A(0),A(1) built; B(0),B(1) DMA'd; ISSUE(2) kept flying ----
  ISSUE(0);
  asm volatile("s_waitcnt vmcnt(0)" ::: "memory");
  CVTW(0);
  ISSUE(1);
  asm volatile("s_waitcnt vmcnt(0)" ::: "memory");
  CVTW(1);
  BDMA(0, 0);
  BDMA(1, 1);
  ISSUE(2);
  asm volatile("s_waitcnt vmcnt(8) lgkmcnt(0)" ::: "memory");  // drain BDMAs+writes, keep ISSUE(2)
  BAR();

  for (int tau = 0; tau < NKT; ++tau) {
    const int d = tau & 1;
    COMPUTE(d);
    // counted wait: drain BDMA(tau+1) (3 oldest); keep ISSUE(tau+2) (8 newest)
    // in flight across the barrier. Tail iters drain fully.
    if (tau <= NKT - 4) asm volatile("s_waitcnt vmcnt(8) lgkmcnt(0)" ::: "memory");
    else                asm volatile("s_waitcnt vmcnt(0) lgkmcnt(0)" ::: "memory");
    BAR();
    if (tau + 2 < NKT) {
      BDMA(d, tau + 2);   // independent loads first — fly under CVTW's wait
      CVTW(d);            // compiler inserts counted wait for ra/rc here
    }
    if (tau + 3 < NKT) ISSUE(tau + 3);
    __builtin_amdgcn_sched_barrier(0);
  }
  asm volatile("s_waitcnt vmcnt(0)" ::: "memory");

  // C-write: rhs[(bk*1024 + it*128 + row)][nt*192 + col] bf16
  unsigned short* Cw = rhs + ((size_t)bk * Nn + it * BM) * TF + nt * BN;
#pragma unroll
  for (int mi = 0; mi < 4; ++mi) {
#pragma unroll
    for (int ni = 0; ni < 3; ++ni) {
      const int col = wn * 48 + ni * 16 + lrow;
      const int row0 = wm * 64 + mi * 16 + c0 * 4;
      unsigned short* op = Cw + (size_t)row0 * TF + col;
      f32x4 v = acc[mi][ni];
#pragma unroll
      for (int q = 0; q < 4; ++q)
        op[(size_t)q * TF] = f2bf(v[q]);
    }
  }
}

// ---------------------------------------------------------------------------
// k4: out[b,t,i,o] = relu( sum_{k,f} rhs[b,k,i,t*32+f] * Theta[k,f,o] )
// (UNCHANGED)
// ---------------------------------------------------------------------------
__global__ __launch_bounds__(256) void k4_epilogue(
    const unsigned short* __restrict__ rhs, const float* __restrict__ theta,
    float* __restrict__ out) {
  __shared__ float th[KC * FIN * FOUT];  // 24 KB, [kf][o]
  const int tid = threadIdx.x;
  for (int s = tid; s < KC * FIN * FOUT; s += 256) th[s] = theta[s];
  __syncthreads();
  const int bid = blockIdx.x;            // (b*12 + t)*4 + ic
  const int ic = bid & 3;
  const int bt = bid >> 2;
  const int t = bt % Tt, b = bt / Tt;
  const int w = tid >> 6, l = tid & 63;
  const int lrow = l & 15;
  const int c0 = l >> 4;
  const int i0 = ic * 256 + w * 64;

  short8 bfrag[KC][4];
#pragma unroll
  for (int ks = 0; ks < KC; ++ks)
#pragma unroll
    for (int oi = 0; oi < 4; ++oi) {
      short8 bf;
#pragma unroll
      for (int rr = 0; rr < 8; ++rr)
        bf[rr] = (short)f2bf(th[(ks * FIN + c0 * 8 + rr) * FOUT + oi * 16 + lrow]);
      bfrag[ks][oi] = bf;
    }

  f32x4 acc[4][4];
#pragma unroll
  for (int mi = 0; mi < 4; ++mi)
#pragma unroll
    for (int oi = 0; oi < 4; ++oi)
      acc[mi][oi] = (f32x4){0.f, 0.f, 0.f, 0.f};

#pragma unroll
  for (int ks = 0; ks < KC; ++ks) {
#pragma unroll
    for (int mi = 0; mi < 4; ++mi) {
      const short8 af = *(const short8*)(
          rhs + ((size_t)(b * KC + ks) * Nn + i0 + mi * 16 + lrow) * TF + t * FIN + c0 * 8);
#pragma unroll
      for (int oi = 0; oi < 4; ++oi)
        acc[mi][oi] = __builtin_amdgcn_mfma_f32_16x16x32_bf16(af, bfrag[ks][oi], acc[mi][oi], 0, 0, 0);
    }
  }

#pragma unroll
  for (int mi = 0; mi < 4; ++mi) {
#pragma unroll
    for (int oi = 0; oi < 4; ++oi) {
      const int row = i0 + mi * 16 + c0 * 4;
      float* op = out + ((size_t)(b * Tt + t) * Nn + row) * FOUT + oi * 16 + lrow;
      f32x4 v = acc[mi][oi];
#pragma unroll
      for (int q = 0; q < 4; ++q)
        op[(size_t)q * FOUT] = fmaxf(v[q], 0.f);
    }
  }
}

// ---------------------------------------------------------------------------
// fallback (ws too small): slow but correct, pure f32
// ---------------------------------------------------------------------------
__global__ __launch_bounds__(128) void k_fallback(
    const float* __restrict__ x, const float* __restrict__ att,
    const float* __restrict__ cheb, const float* __restrict__ theta,
    float* __restrict__ out) {
  const int blk = blockIdx.x;  // (b, t, i)
  const int i = blk & 1023;
  const int bt = blk >> 10;
  const int t = bt % Tt, b = bt / Tt;
  __shared__ float rhs[KC * FIN];
  const int tid = threadIdx.x;
  if (tid < KC * FIN) {
    const int k = tid >> 5, f = tid & 31;
    const float* ar = att + ((size_t)b * Nn + i) * Nn;
    const float* cr = cheb + ((size_t)k * Nn + i) * Nn;
    const float* xr = x + ((size_t)(b * Tt + t) * Nn) * FIN + f;
    float s = 0.f;
    for (int j = 0; j < Nn; ++j) s = fmaf(ar[j] * cr[j], xr[(size_t)j * FIN], s);
    rhs[tid] = s;
  }
  __syncthreads();
  if (tid < FOUT) {
    float a = 0.f;
#pragma unroll
    for (int kf = 0; kf < KC * FIN; ++kf) a = fmaf(rhs[kf], theta[kf * FOUT + tid], a);
    out[((size_t)(b * Tt + t) * Nn + i) * FOUT + tid] = fmaxf(a, 0.f);
  }
}

extern "C" void kernel_launch(void* const* d_in, const int* in_sizes, int n_in,
                              void* d_out, int out_size, void* d_ws, size_t ws_size,
                              hipStream_t stream) {
  const float* x     = (const float*)d_in[0];
  const float* att   = (const float*)d_in[1];
  const float* cheb  = (const float*)d_in[2];
  const float* theta = (const float*)d_in[3];
  float* out = (float*)d_out;

  const size_t needYx = (size_t)Bb * TF * Nn * sizeof(unsigned short);      // 12.6 MB
  const size_t needR  = (size_t)Bb * KC * Nn * TF * sizeof(unsigned short); // 37.7 MB
  if (ws_size >= needYx + needR) {
    unsigned short* YxT = (unsigned short*)d_ws;
    unsigned short* rhs = (unsigned short*)((char*)d_ws + needYx);
    hipLaunchKernelGGL(k2r_build_YxT, dim3(Bb * Tt * 4), dim3(256), 0, stream,
                       x, YxT);
    hipLaunchKernelGGL(k3f_gemm, dim3(48 * (Nn / BM) * (TF / BN)), dim3(512), 0, stream,
                       att, cheb, YxT, rhs);
    hipLaunchKernelGGL(k4_epilogue, dim3(Bb * Tt * 4), dim3(256), 0, stream,
                       rhs, theta, out);
  } else {
    hipLaunchKernelGGL(k_fallback, dim3(Bb * Tt * Nn), dim3(128), 0, stream,
                       x, att, cheb, theta, out);
  }
}